// Round 11
// baseline (828.008 us; speedup 1.0000x reference)
//
#include <hip/hip_runtime.h>
#include <hip/hip_bf16.h>

#define DEMB 64
typedef unsigned short u16;

__device__ __forceinline__ u16 f2bf(float f) {
    union { float f; unsigned int i; } c; c.f = f;
    unsigned int r = c.i + 0x7FFF + ((c.i >> 16) & 1);
    return (u16)(r >> 16);
}
__device__ __forceinline__ float lo16(unsigned int w) {
    union { unsigned int i; float f; } c; c.i = w << 16; return c.f;
}
__device__ __forceinline__ float hi16(unsigned int w) {
    union { unsigned int i; float f; } c; c.i = w & 0xFFFF0000u; return c.f;
}

// odd 7th-order minimax tanh on [-1.02, 1.02], abs err <= ~3e-4
__device__ __forceinline__ float ptanh5(float a) {
    float a2 = a * a;
    float t = fmaf(a2, -0.030095f, 0.124066f);
    t = fmaf(a2, t, -0.332377f);
    t = fmaf(a2, t, 1.0f);
    return a * t;
}

__global__ void init_A_kernel(float4* __restrict__ A, int E) {
    int e = blockIdx.x * blockDim.x + threadIdx.x;
    if (e < E) A[e] = make_float4(1.f, 1.f, 1.f, 1.f);
}

__global__ void concat_copy_kernel(const float* __restrict__ u, const float* __restrict__ it,
                                   float* __restrict__ x, float* __restrict__ acc,
                                   int nu_elems, int total) {
    int i = blockIdx.x * blockDim.x + threadIdx.x;
    if (i >= total) return;
    float v = (i < nu_elems) ? u[i] : it[i - nu_elems];
    x[i] = v;
    acc[i] = v;
}

// ============ CSR build: deterministic histogram radix, padded ranges ============
__global__ void hist_kernel(const int* __restrict__ h, int* __restrict__ ghist,
                            int E, int EPB, int NB) {
    __shared__ int bins[1024];
    int b = blockIdx.x, tid = threadIdx.x;
    for (int j = tid; j < NB; j += 256) bins[j] = 0;
    __syncthreads();
    int s = b * EPB, e = min(s + EPB, E);
    for (int k = s + tid; k < e; k += 256)
        atomicAdd(&bins[((unsigned)h[k]) >> 8], 1);
    __syncthreads();
    for (int j = tid; j < NB; j += 256) ghist[j * gridDim.x + b] = bins[j];
}

__global__ void btot_kernel(const int* __restrict__ ghist, int* __restrict__ btot) {
    __shared__ int s[256];
    int j = blockIdx.x, tid = threadIdx.x;
    s[tid] = ghist[j * 256 + tid];
    __syncthreads();
    for (int o = 128; o >= 1; o >>= 1) {
        if (tid < o) s[tid] += s[tid + o];
        __syncthreads();
    }
    if (tid == 0) btot[j] = s[0];
}

// single block: exclusive scan (generic)
__global__ void bscan_kernel(const int* __restrict__ in, int* __restrict__ outp,
                             int NB, int tail) {
    __shared__ int s[1024];
    int tid = threadIdx.x;
    int v = (tid < NB) ? in[tid] : 0;
    s[tid] = v;
    __syncthreads();
    for (int o = 1; o < 1024; o <<= 1) {
        int a = (tid >= o) ? s[tid - o] : 0;
        __syncthreads();
        s[tid] += a;
        __syncthreads();
    }
    if (tid < NB) outp[tid] = s[tid] - v;
    if (tid == 0) outp[NB] = tail;
}

__global__ void bofs_kernel(int* __restrict__ ghist, const int* __restrict__ bbase) {
    __shared__ int s[256];
    int j = blockIdx.x, tid = threadIdx.x;
    int v = ghist[j * 256 + tid];
    s[tid] = v;
    __syncthreads();
    for (int o = 1; o < 256; o <<= 1) {
        int a = (tid >= o) ? s[tid - o] : 0;
        __syncthreads();
        s[tid] += a;
        __syncthreads();
    }
    ghist[j * 256 + tid] = bbase[j] + s[tid] - v;
}

__global__ void scatter_kernel(const int* __restrict__ h, const int* __restrict__ t,
                               const int* __restrict__ ghist, unsigned* __restrict__ stg,
                               int E, int EPB, int NB) {
    __shared__ int cur[1024];
    int b = blockIdx.x, tid = threadIdx.x;
    for (int j = tid; j < NB; j += 256) cur[j] = ghist[j * gridDim.x + b];
    __syncthreads();
    int s = b * EPB, e = min(s + EPB, E);
    for (int k = s + tid; k < e; k += 256) {
        unsigned hh = (unsigned)h[k];
        int pos = atomicAdd(&cur[hh >> 8], 1);
        stg[pos] = ((hh & 255u) << 18) | (unsigned)t[k];
    }
}

// pass A: per-node degree + per-bucket padded total
__global__ void finalize_a_kernel(const unsigned* __restrict__ stg, const int* __restrict__ bbase,
                                  int* __restrict__ deg, int* __restrict__ ptot, int N) {
    __shared__ int cnt[256];
    __shared__ int red[256];
    int b = blockIdx.x, tid = threadIdx.x;
    int ebeg = bbase[b], eend = bbase[b + 1];
    cnt[tid] = 0;
    __syncthreads();
    for (int k = ebeg + tid; k < eend; k += 256)
        atomicAdd(&cnt[(stg[k] >> 18) & 255u], 1);
    __syncthreads();
    int d = cnt[tid];
    int gn = (b << 8) + tid;
    if (gn < N) deg[gn] = d;
    int pd = (d + 3) & ~3;
    red[tid] = pd;
    __syncthreads();
    for (int o = 128; o >= 1; o >>= 1) {
        if (tid < o) red[tid] += red[tid + o];
        __syncthreads();
    }
    if (tid == 0) ptot[b] = red[0];
}

// pass B: padded AND unpadded per-node offsets + scatter csr_t + pad fill (-> node N)
__global__ void finalize_b_kernel(const unsigned* __restrict__ stg, const int* __restrict__ bbase,
                                  const int* __restrict__ pbase2, const int* __restrict__ deg,
                                  int* __restrict__ off_pad, int* __restrict__ off_upad,
                                  int* __restrict__ csr_t, int N) {
    __shared__ int scn[256];
    __shared__ int scn2[256];
    __shared__ int cur[256];
    int b = blockIdx.x, tid = threadIdx.x;
    int ebeg = bbase[b], eend = bbase[b + 1];
    int gn = (b << 8) + tid;
    int d = (gn < N) ? deg[gn] : 0;
    int pd = (d + 3) & ~3;
    scn[tid] = pd;
    scn2[tid] = d;
    __syncthreads();
    for (int o = 1; o < 256; o <<= 1) {
        int a = (tid >= o) ? scn[tid - o] : 0;
        int a2 = (tid >= o) ? scn2[tid - o] : 0;
        __syncthreads();
        scn[tid] += a;
        scn2[tid] += a2;
        __syncthreads();
    }
    int pexcl = scn[tid] - pd;
    int uexcl = scn2[tid] - d;
    int pb = pbase2[b];
    int base = pb + pexcl;
    if (gn < N) {
        off_pad[gn] = base;
        off_upad[gn] = ebeg + uexcl;   // unpadded edge index (A/prob space)
    }
    cur[tid] = pexcl;
    __syncthreads();
    for (int k = ebeg + tid; k < eend; k += 256) {
        unsigned en = stg[k];
        int slot = atomicAdd(&cur[(en >> 18) & 255u], 1);
        csr_t[pb + slot] = (int)(en & 0x3FFFFu);
    }
    __syncthreads();
    for (int q = d; q < pd; q++) csr_t[base + q] = N;   // dummy pads
}

// bootstrap: prob=0.25 folded -> dcol0 = 0.5/sqrt(deg); zero the pad node N
__global__ void dcol0_kernel(const int* __restrict__ deg, float* __restrict__ dcolA,
                             float* __restrict__ dcolB, int N) {
    int n = blockIdx.x * blockDim.x + threadIdx.x;
    if (n > N) return;
    float v = (n < N) ? 0.5f * rsqrtf((float)deg[n]) : 0.f;
    *(float4*)(dcolA + (size_t)n * 4) = make_float4(v, v, v, v);
    if (n == N) *(float4*)(dcolB + (size_t)n * 4) = make_float4(0.f, 0.f, 0.f, 0.f);
}

// ============ per-layer: xs = bf16(x); tailt = bf16(tanh(x/||x_f||)); row N = 0
__global__ void prep_kernel(const float* __restrict__ x, u16* __restrict__ xs,
                            u16* __restrict__ tailt, int total) {
    int i = blockIdx.x * blockDim.x + threadIdx.x;
    if (i >= total + DEMB) return;
    float v = (i < total) ? x[i] : 0.f;
    xs[i] = f2bf(v);
    float s = v * v;
#pragma unroll
    for (int o = 8; o >= 1; o >>= 1) s += __shfl_xor(s, o);
    float nr = fmaxf(sqrtf(s), 1e-12f);
    tailt[i] = f2bf(ptanh5(v * __builtin_amdgcn_rcpf(nr)));
}

// ============ fused message + routing + next-iteration softmax/dcol
// One 64-lane wave per node. lane l: g=l>>4 (edge slot), m=l&15 (col quad), f=m>>2.
// Padded CSR (csr_t in padded space; pads -> zero-row node N). A/prob stay in
// UNPADDED space: node n's kk-th slot edge -> off_upad[n]+kk+g (pads read a
// neighbor's finite values, masked from stores/rowsum; xs zero-row kills loop1).
template <bool UNI, bool WOUT, bool ROUTE>
__global__ void message_kernel(const int* __restrict__ off_pad, const int* __restrict__ off_upad,
                               const int* __restrict__ deg, const int* __restrict__ csr_t,
                               float* __restrict__ Acsr, float* __restrict__ prob,
                               const u16* __restrict__ xs, const u16* __restrict__ tailt,
                               const float* __restrict__ dcol_in, float* __restrict__ dcol_out,
                               float* __restrict__ out, int N) {
    int gid = blockIdx.x * blockDim.x + threadIdx.x;
    int n = gid >> 6;
    if (n >= N) return;
    int l = gid & 63;
    int g = l >> 4;
    int m = l & 15;
    int f = m >> 2;
    int s = off_pad[n];
    int dg = deg[n];
    int dp = (dg + 3) & ~3;
    const int* ct = csr_t + s;
    unsigned pbase = (unsigned)off_upad[n] * 4u + (unsigned)(g * 4 + f);
    unsigned moff = (unsigned)(m << 2);

    float a0 = 0.f, a1 = 0.f, a2 = 0.f, a3 = 0.f;

#pragma unroll 2
    for (int kk = 0; kk < dp; kk += 4) {
        unsigned t1 = (unsigned)ct[kk + g];
        float p1;
        if (UNI) {
            p1 = dcol_in[t1 * 4u + (unsigned)f];
        } else {
            p1 = prob[pbase + (unsigned)kk * 4u] * dcol_in[t1 * 4u + (unsigned)f];
        }
        const uint2 x1 = *(const uint2*)(xs + (t1 << 6) + moff);
        a0 += p1 * lo16(x1.x);
        a1 += p1 * hi16(x1.x);
        a2 += p1 * lo16(x1.y);
        a3 += p1 * hi16(x1.y);
    }

    // combine the 4 edge slots
    a0 += __shfl_xor(a0, 16); a1 += __shfl_xor(a1, 16);
    a2 += __shfl_xor(a2, 16); a3 += __shfl_xor(a3, 16);
    a0 += __shfl_xor(a0, 32); a1 += __shfl_xor(a1, 32);
    a2 += __shfl_xor(a2, 32); a3 += __shfl_xor(a3, 32);

    if (WOUT) {
        float dn = dcol_in[(unsigned)n * 4u + (unsigned)f];
        if (l < 16) {
            *(float4*)(out + ((unsigned)n << 6) + moff) =
                make_float4(a0 * dn, a1 * dn, a2 * dn, a3 * dn);
        }
    }
    if (!ROUTE) return;

    // head = l2norm per factor (dcol[n] scale-invariant)
    float ss = a0 * a0 + a1 * a1 + a2 * a2 + a3 * a3;
    ss += __shfl_xor(ss, 1);
    ss += __shfl_xor(ss, 2);
    float inv = 1.0f / fmaxf(sqrtf(ss), 1e-12f);
    float h0 = a0 * inv, h1 = a1 * inv, h2 = a2 * inv, h3 = a3 * inv;

    float rowsumf = 0.f;

#pragma unroll 2
    for (int kk = 0; kk < dp; kk += 4) {
        unsigned t1 = (unsigned)ct[kk + g];
        const uint2 tv1 = *(const uint2*)(tailt + (t1 << 6) + moff);
        float d1 = h0 * lo16(tv1.x) + h1 * hi16(tv1.x)
                 + h2 * lo16(tv1.y) + h3 * hi16(tv1.y);
        d1 += __shfl_xor(d1, 1); d1 += __shfl_xor(d1, 2);
        unsigned ai = pbase + (unsigned)kk * 4u;
        float na1 = Acsr[ai] + d1;           // pad: neighbor's finite value
        float ex1 = __expf(na1);             // no max-sub: |A|<=13 analytically
        float se1 = ex1 + __shfl_xor(ex1, 4); se1 += __shfl_xor(se1, 8);
        float p1 = ex1 * __builtin_amdgcn_rcpf(se1);
        bool v1 = (kk + g) < dg;
        if ((m & 3) == 0 && v1) { Acsr[ai] = na1; prob[ai] = p1; }
        rowsumf += v1 ? p1 : 0.f;
    }

    rowsumf += __shfl_xor(rowsumf, 16);
    rowsumf += __shfl_xor(rowsumf, 32);
    if (l < 16 && (m & 3) == 0) dcol_out[(unsigned)n * 4u + (unsigned)f] = rsqrtf(rowsumf);
}

// acc += v; if final, acc = (acc + v) / 3
__global__ void acc_kernel(float* __restrict__ acc, const float* __restrict__ v, int n, int final_) {
    int i = blockIdx.x * blockDim.x + threadIdx.x;
    if (i >= n) return;
    float r = acc[i] + v[i];
    acc[i] = final_ ? r * (1.0f / 3.0f) : r;
}

extern "C" void kernel_launch(void* const* d_in, const int* in_sizes, int n_in,
                              void* d_out, int out_size, void* d_ws, size_t ws_size,
                              hipStream_t stream) {
    const float* user_emb = (const float*)d_in[0];
    const float* item_emb = (const float*)d_in[1];
    const int* h = (const int*)d_in[2];
    const int* t = (const int*)d_in[3];

    const int nu_elems = in_sizes[0];
    const int ni_elems = in_sizes[1];
    const int total = nu_elems + ni_elems;   // N * 64
    const int N = total / DEMB;
    const int E = in_sizes[2];
    const int NB = (N + 255) >> 8;           // buckets (<= 1024)
    const int NBLK = 256;
    const int EPB = (E + NBLK - 1) / NBLK;
    const int EPAD = E + 3 * N + 256;        // upper bound on padded edge count

    float* acc = (float*)d_out;

    // ---- workspace layout ----
    float* x     = (float*)d_ws;                    // total f32
    float* out   = x + (size_t)total;               // total f32
    float* Acsr  = out + (size_t)total;             // 4E f32 (unpadded edge space)
    float* prob  = Acsr + (size_t)4 * E;            // 4E f32 (first E aliased as stg)
    float* dcolA = prob + (size_t)4 * E;            // 4(N+1) f32
    float* dcolB = dcolA + (size_t)4 * (N + 1);     // 4(N+1) f32
    u16* xs      = (u16*)(dcolB + (size_t)4 * (N + 1)); // total+64 u16
    u16* tailt   = xs + (size_t)(total + DEMB);     // total+64 u16
    int* ghist   = (int*)(tailt + (size_t)(total + DEMB)); // NB*256
    int* btot    = ghist + (size_t)NB * 256;        // NB
    int* ptot    = btot + ((NB + 3) & ~3);          // NB
    int* bbase   = ptot + ((NB + 3) & ~3);          // NB+1
    int* pbase2  = bbase + ((NB + 5) & ~3);         // NB+1
    int* deg     = pbase2 + ((NB + 5) & ~3);        // N
    int* off_pad = deg + ((N + 3) & ~3);            // N
    int* off_upad= off_pad + ((N + 3) & ~3);        // N
    int* csr_t   = off_upad + ((N + 3) & ~3);       // EPAD
    unsigned* stg = (unsigned*)prob;                // E (time-disjoint with prob)

    const int BLK = 256;
    const int gE = (E + BLK - 1) / BLK;
    const int gTot = (total + BLK - 1) / BLK;
    const int gTot2 = (total + DEMB + BLK - 1) / BLK;
    const int gN1 = (N + 1 + BLK - 1) / BLK;
    const int gNodeWave = (N * 64 + BLK - 1) / BLK;

    concat_copy_kernel<<<gTot, BLK, 0, stream>>>(user_emb, item_emb, x, acc, nu_elems, total);

    // CSR build (deterministic, padded csr_t; unpadded A/prob offsets)
    hist_kernel<<<NBLK, 256, 0, stream>>>(h, ghist, E, EPB, NB);
    btot_kernel<<<NB, 256, 0, stream>>>(ghist, btot);
    bscan_kernel<<<1, 1024, 0, stream>>>(btot, bbase, NB, E);
    bofs_kernel<<<NB, 256, 0, stream>>>(ghist, bbase);
    scatter_kernel<<<NBLK, 256, 0, stream>>>(h, t, ghist, stg, E, EPB, NB);
    finalize_a_kernel<<<NB, 256, 0, stream>>>(stg, bbase, deg, ptot, N);
    bscan_kernel<<<1, 1024, 0, stream>>>(ptot, pbase2, NB, 0);
    finalize_b_kernel<<<NB, 256, 0, stream>>>(stg, bbase, pbase2, deg, off_pad, off_upad,
                                              csr_t, N);

    init_A_kernel<<<gE, BLK, 0, stream>>>((float4*)Acsr, E);
    dcol0_kernel<<<gN1, BLK, 0, stream>>>(deg, dcolA, dcolB, N);

    // ---- layer 0 ----
    prep_kernel<<<gTot2, BLK, 0, stream>>>(x, xs, tailt, total);
    message_kernel<true, false, true><<<gNodeWave, BLK, 0, stream>>>(
        off_pad, off_upad, deg, csr_t, Acsr, prob, xs, tailt, dcolA, dcolB, out, N);
    message_kernel<false, true, true><<<gNodeWave, BLK, 0, stream>>>(
        off_pad, off_upad, deg, csr_t, Acsr, prob, xs, tailt, dcolB, dcolA, out, N);
    acc_kernel<<<gTot, BLK, 0, stream>>>(acc, out, total, 0);

    // ---- layer 1 ----
    prep_kernel<<<gTot2, BLK, 0, stream>>>(out, xs, tailt, total);
    message_kernel<false, false, true><<<gNodeWave, BLK, 0, stream>>>(
        off_pad, off_upad, deg, csr_t, Acsr, prob, xs, tailt, dcolA, dcolB, x, N);
    message_kernel<false, true, false><<<gNodeWave, BLK, 0, stream>>>(
        off_pad, off_upad, deg, csr_t, Acsr, prob, xs, tailt, dcolB, dcolA, x, N);
    acc_kernel<<<gTot, BLK, 0, stream>>>(acc, x, total, 1);
}

// Round 12
// 590.122 us; speedup vs baseline: 1.4031x; 1.4031x over previous
//
#include <hip/hip_runtime.h>
#include <hip/hip_bf16.h>

#define DEMB 64
typedef unsigned short u16;
typedef float f32x2 __attribute__((ext_vector_type(2)));

__device__ __forceinline__ u16 f2bf(float f) {
    union { float f; unsigned int i; } c; c.f = f;
    unsigned int r = c.i + 0x7FFF + ((c.i >> 16) & 1);
    return (u16)(r >> 16);
}
__device__ __forceinline__ float lo16(unsigned int w) {
    union { unsigned int i; float f; } c; c.i = w << 16; return c.f;
}
__device__ __forceinline__ float hi16(unsigned int w) {
    union { unsigned int i; float f; } c; c.i = w & 0xFFFF0000u; return c.f;
}

// odd 7th-order minimax tanh on [-1.02, 1.02], abs err <= ~3e-4
__device__ __forceinline__ float ptanh5(float a) {
    float a2 = a * a;
    float t = fmaf(a2, -0.030095f, 0.124066f);
    t = fmaf(a2, t, -0.332377f);
    t = fmaf(a2, t, 1.0f);
    return a * t;
}

__global__ void init_A_kernel(float4* __restrict__ A, int E) {
    int e = blockIdx.x * blockDim.x + threadIdx.x;
    if (e < E) A[e] = make_float4(1.f, 1.f, 1.f, 1.f);
}

__global__ void concat_copy_kernel(const float* __restrict__ u, const float* __restrict__ it,
                                   float* __restrict__ x, float* __restrict__ acc,
                                   int nu_elems, int total) {
    int i = blockIdx.x * blockDim.x + threadIdx.x;
    if (i >= total) return;
    float v = (i < nu_elems) ? u[i] : it[i - nu_elems];
    x[i] = v;
    acc[i] = v;
}

// ============ CSR build: deterministic histogram radix (R9-proven) ============
__global__ void hist_kernel(const int* __restrict__ h, int* __restrict__ ghist,
                            int E, int EPB, int NB) {
    __shared__ int bins[1024];
    int b = blockIdx.x, tid = threadIdx.x;
    for (int j = tid; j < NB; j += 256) bins[j] = 0;
    __syncthreads();
    int s = b * EPB, e = min(s + EPB, E);
    for (int k = s + tid; k < e; k += 256)
        atomicAdd(&bins[((unsigned)h[k]) >> 8], 1);
    __syncthreads();
    for (int j = tid; j < NB; j += 256) ghist[j * gridDim.x + b] = bins[j];
}

__global__ void btot_kernel(const int* __restrict__ ghist, int* __restrict__ btot) {
    __shared__ int s[256];
    int j = blockIdx.x, tid = threadIdx.x;
    s[tid] = ghist[j * 256 + tid];
    __syncthreads();
    for (int o = 128; o >= 1; o >>= 1) {
        if (tid < o) s[tid] += s[tid + o];
        __syncthreads();
    }
    if (tid == 0) btot[j] = s[0];
}

__global__ void bscan_kernel(const int* __restrict__ btot, int* __restrict__ bbase,
                             int NB, int E) {
    __shared__ int s[1024];
    int tid = threadIdx.x;
    int v = (tid < NB) ? btot[tid] : 0;
    s[tid] = v;
    __syncthreads();
    for (int o = 1; o < 1024; o <<= 1) {
        int a = (tid >= o) ? s[tid - o] : 0;
        __syncthreads();
        s[tid] += a;
        __syncthreads();
    }
    if (tid < NB) bbase[tid] = s[tid] - v;
    if (tid == 0) bbase[NB] = E;
}

__global__ void bofs_kernel(int* __restrict__ ghist, const int* __restrict__ bbase) {
    __shared__ int s[256];
    int j = blockIdx.x, tid = threadIdx.x;
    int v = ghist[j * 256 + tid];
    s[tid] = v;
    __syncthreads();
    for (int o = 1; o < 256; o <<= 1) {
        int a = (tid >= o) ? s[tid - o] : 0;
        __syncthreads();
        s[tid] += a;
        __syncthreads();
    }
    ghist[j * 256 + tid] = bbase[j] + s[tid] - v;
}

__global__ void scatter_kernel(const int* __restrict__ h, const int* __restrict__ t,
                               const int* __restrict__ ghist, unsigned* __restrict__ stg,
                               int E, int EPB, int NB) {
    __shared__ int cur[1024];
    int b = blockIdx.x, tid = threadIdx.x;
    for (int j = tid; j < NB; j += 256) cur[j] = ghist[j * gridDim.x + b];
    __syncthreads();
    int s = b * EPB, e = min(s + EPB, E);
    for (int k = s + tid; k < e; k += 256) {
        unsigned hh = (unsigned)h[k];
        int pos = atomicAdd(&cur[hh >> 8], 1);
        stg[pos] = ((hh & 255u) << 18) | (unsigned)t[k];
    }
}

__global__ void finalize_kernel(const unsigned* __restrict__ stg, const int* __restrict__ bbase,
                                int* __restrict__ off, int* __restrict__ csr_t, int N, int E) {
    __shared__ int cnt[256];
    __shared__ int scn[256];
    int b = blockIdx.x, tid = threadIdx.x;
    int ebeg = bbase[b], eend = bbase[b + 1];
    cnt[tid] = 0;
    __syncthreads();
    for (int k = ebeg + tid; k < eend; k += 256)
        atomicAdd(&cnt[(stg[k] >> 18) & 255u], 1);
    __syncthreads();
    int v = cnt[tid];
    scn[tid] = v;
    __syncthreads();
    for (int o = 1; o < 256; o <<= 1) {
        int a = (tid >= o) ? scn[tid - o] : 0;
        __syncthreads();
        scn[tid] += a;
        __syncthreads();
    }
    int excl = scn[tid] - v;
    int gn = (b << 8) + tid;
    if (gn < N) off[gn] = ebeg + excl;
    if (b == 0 && tid == 0) off[N] = E;
    __syncthreads();
    cnt[tid] = excl;   // reuse as cursor
    __syncthreads();
    for (int k = ebeg + tid; k < eend; k += 256) {
        unsigned en = stg[k];
        int slot = atomicAdd(&cnt[(en >> 18) & 255u], 1);
        csr_t[ebeg + slot] = (int)(en & 0x3FFFFu);
    }
}

// bootstrap: prob=0.25 folded -> dcol0 = 0.5/sqrt(deg)
__global__ void dcol0_kernel(const int* __restrict__ off, float* __restrict__ dcol, int N) {
    int n = blockIdx.x * blockDim.x + threadIdx.x;
    if (n >= N) return;
    float v = 0.5f * rsqrtf((float)(off[n + 1] - off[n]));
    *(float4*)(dcol + (size_t)n * 4) = make_float4(v, v, v, v);
}

// ============ per-layer: xs = bf16(x); tailt = bf16(tanh(x/||x_f||))
__global__ void prep_kernel(const float* __restrict__ x, u16* __restrict__ xs,
                            u16* __restrict__ tailt, int total) {
    int i = blockIdx.x * blockDim.x + threadIdx.x;
    if (i >= total) return;
    float v = x[i];
    xs[i] = f2bf(v);
    float s = v * v;
#pragma unroll
    for (int o = 8; o >= 1; o >>= 1) s += __shfl_xor(s, o);
    float nr = fmaxf(sqrtf(s), 1e-12f);
    tailt[i] = f2bf(ptanh5(v * __builtin_amdgcn_rcpf(nr)));
}

// ============ fused message + routing + next-iteration softmax/dcol
// One 64-lane wave per node. lane l: g=l>>4 (edge slot), m=l&15 (col quad), f=m>>2.
// R9 structure; 32-bit offsets; packed f32x2 FMA; acc fused into epilogue.
// ACC: 0=none, 1=acc+=val, 2=acc=(acc+val)/3 (final mean, out not written)
template <bool UNI, bool WOUT, bool ROUTE, int ACC>
__global__ void message_kernel(const int* __restrict__ off, const int* __restrict__ csr_t,
                               float* __restrict__ Acsr, float* __restrict__ prob,
                               const u16* __restrict__ xs, const u16* __restrict__ tailt,
                               const float* __restrict__ dcol_in, float* __restrict__ dcol_out,
                               float* __restrict__ out, float* __restrict__ acc, int N) {
    int gid = blockIdx.x * blockDim.x + threadIdx.x;
    int n = gid >> 6;
    if (n >= N) return;
    int l = gid & 63;
    int g = l >> 4;
    int m = l & 15;
    unsigned f = (unsigned)(m >> 2);
    int s = off[n], e = off[n + 1];
    unsigned moff = (unsigned)(m << 2);

    f32x2 a01 = {0.f, 0.f}, a23 = {0.f, 0.f};

#pragma unroll 2
    for (int k = s; k < e; k += 8) {
        int e1 = k + g, e2 = e1 + 4;
        bool v1 = e1 < e, v2 = e2 < e;
        unsigned c1 = (unsigned)(v1 ? e1 : s);
        unsigned c2 = (unsigned)(v2 ? e2 : s);
        unsigned t1 = (unsigned)csr_t[c1];
        unsigned t2 = (unsigned)csr_t[c2];
        float p1, p2;
        if (UNI) {
            p1 = dcol_in[t1 * 4u + f];
            p2 = dcol_in[t2 * 4u + f];
        } else {
            p1 = prob[c1 * 4u + f] * dcol_in[t1 * 4u + f];
            p2 = prob[c2 * 4u + f] * dcol_in[t2 * 4u + f];
        }
        p1 = v1 ? p1 : 0.f;
        p2 = v2 ? p2 : 0.f;
        const uint2 x1 = *(const uint2*)(xs + (t1 << 6) + moff);
        const uint2 x2 = *(const uint2*)(xs + (t2 << 6) + moff);
        f32x2 xa = {lo16(x1.x), hi16(x1.x)};
        f32x2 xb = {lo16(x1.y), hi16(x1.y)};
        f32x2 ya = {lo16(x2.x), hi16(x2.x)};
        f32x2 yb = {lo16(x2.y), hi16(x2.y)};
        a01 += p1 * xa + p2 * ya;   // v_pk_fma_f32
        a23 += p1 * xb + p2 * yb;
    }

    float a0 = a01.x, a1 = a01.y, a2 = a23.x, a3 = a23.y;
    // combine the 4 edge slots
    a0 += __shfl_xor(a0, 16); a1 += __shfl_xor(a1, 16);
    a2 += __shfl_xor(a2, 16); a3 += __shfl_xor(a3, 16);
    a0 += __shfl_xor(a0, 32); a1 += __shfl_xor(a1, 32);
    a2 += __shfl_xor(a2, 32); a3 += __shfl_xor(a3, 32);

    if (WOUT || ACC != 0) {
        float dn = dcol_in[(unsigned)n * 4u + f];
        if (l < 16) {
            unsigned oidx = ((unsigned)n << 6) + moff;
            float4 val = make_float4(a0 * dn, a1 * dn, a2 * dn, a3 * dn);
            if (WOUT) *(float4*)(out + oidx) = val;
            if (ACC == 1) {
                float4 c = *(const float4*)(acc + oidx);
                *(float4*)(acc + oidx) =
                    make_float4(c.x + val.x, c.y + val.y, c.z + val.z, c.w + val.w);
            } else if (ACC == 2) {
                const float k3 = 1.0f / 3.0f;
                float4 c = *(const float4*)(acc + oidx);
                *(float4*)(acc + oidx) =
                    make_float4((c.x + val.x) * k3, (c.y + val.y) * k3,
                                (c.z + val.z) * k3, (c.w + val.w) * k3);
            }
        }
    }
    if (!ROUTE) return;

    // head = l2norm per factor (dcol[n] scale-invariant)
    float ss = a0 * a0 + a1 * a1 + a2 * a2 + a3 * a3;
    ss += __shfl_xor(ss, 1);
    ss += __shfl_xor(ss, 2);
    float inv = 1.0f / fmaxf(sqrtf(ss), 1e-12f);
    f32x2 h01 = {a0 * inv, a1 * inv};
    f32x2 h23 = {a2 * inv, a3 * inv};

    float rowsumf = 0.f;

#pragma unroll 2
    for (int k = s; k < e; k += 8) {
        int e1 = k + g, e2 = e1 + 4;
        bool v1 = e1 < e, v2 = e2 < e;
        unsigned c1 = (unsigned)(v1 ? e1 : s);
        unsigned c2 = (unsigned)(v2 ? e2 : s);
        unsigned t1 = (unsigned)csr_t[c1];
        unsigned t2 = (unsigned)csr_t[c2];
        const uint2 tv1 = *(const uint2*)(tailt + (t1 << 6) + moff);
        const uint2 tv2 = *(const uint2*)(tailt + (t2 << 6) + moff);
        f32x2 dv1 = h01 * (f32x2){lo16(tv1.x), hi16(tv1.x)}
                  + h23 * (f32x2){lo16(tv1.y), hi16(tv1.y)};
        f32x2 dv2 = h01 * (f32x2){lo16(tv2.x), hi16(tv2.x)}
                  + h23 * (f32x2){lo16(tv2.y), hi16(tv2.y)};
        float d1 = dv1.x + dv1.y;
        float d2 = dv2.x + dv2.y;
        d1 += __shfl_xor(d1, 1); d1 += __shfl_xor(d1, 2);
        d2 += __shfl_xor(d2, 1); d2 += __shfl_xor(d2, 2);
        unsigned ai1 = c1 * 4u + f;
        unsigned ai2 = c2 * 4u + f;
        float na1 = Acsr[ai1] + d1;
        float na2 = Acsr[ai2] + d2;
        // softmax over the 4 factors (lane bits 2..3 of m), no max-sub: |A|<=13
        float ex1 = __expf(na1);
        float ex2 = __expf(na2);
        float se1 = ex1 + __shfl_xor(ex1, 4); se1 += __shfl_xor(se1, 8);
        float se2 = ex2 + __shfl_xor(ex2, 4); se2 += __shfl_xor(se2, 8);
        float p1 = ex1 * __builtin_amdgcn_rcpf(se1);
        float p2 = ex2 * __builtin_amdgcn_rcpf(se2);
        if ((m & 3) == 0) {
            if (v1) { Acsr[ai1] = na1; prob[ai1] = p1; }
            if (v2) { Acsr[ai2] = na2; prob[ai2] = p2; }
        }
        rowsumf += (v1 ? p1 : 0.f) + (v2 ? p2 : 0.f);
    }

    rowsumf += __shfl_xor(rowsumf, 16);
    rowsumf += __shfl_xor(rowsumf, 32);
    if (l < 16 && (m & 3) == 0) dcol_out[(unsigned)n * 4u + f] = rsqrtf(rowsumf);
}

extern "C" void kernel_launch(void* const* d_in, const int* in_sizes, int n_in,
                              void* d_out, int out_size, void* d_ws, size_t ws_size,
                              hipStream_t stream) {
    const float* user_emb = (const float*)d_in[0];
    const float* item_emb = (const float*)d_in[1];
    const int* h = (const int*)d_in[2];
    const int* t = (const int*)d_in[3];

    const int nu_elems = in_sizes[0];
    const int ni_elems = in_sizes[1];
    const int total = nu_elems + ni_elems;   // N * 64
    const int N = total / DEMB;
    const int E = in_sizes[2];
    const int NB = (N + 255) >> 8;           // buckets (<= 1024)
    const int NBLK = 256;
    const int EPB = (E + NBLK - 1) / NBLK;

    float* acc = (float*)d_out;

    // ---- workspace layout (R9) ----
    float* x     = (float*)d_ws;                    // total f32
    float* out   = x + (size_t)total;               // total f32
    float* Acsr  = out + (size_t)total;             // 4E f32
    float* prob  = Acsr + (size_t)4 * E;            // 4E f32 (first E aliased as stg)
    float* dcolA = prob + (size_t)4 * E;            // 4N f32
    float* dcolB = dcolA + (size_t)4 * N;           // 4N f32
    u16* xs      = (u16*)(dcolB + (size_t)4 * N);   // total u16
    u16* tailt   = xs + (size_t)total;              // total u16
    int* ghist   = (int*)(tailt + (size_t)total);   // NB*256
    int* btot    = ghist + (size_t)NB * 256;        // NB
    int* bbase   = btot + ((NB + 3) & ~3);          // NB+1
    int* off     = bbase + ((NB + 5) & ~3);         // N+1
    int* csr_t   = off + ((N + 4) & ~3);            // E
    unsigned* stg = (unsigned*)prob;                // E (time-disjoint with prob)

    const int BLK = 256;
    const int gE = (E + BLK - 1) / BLK;
    const int gTot = (total + BLK - 1) / BLK;
    const int gN = (N + BLK - 1) / BLK;
    const int gNodeWave = (N * 64 + BLK - 1) / BLK;

    concat_copy_kernel<<<gTot, BLK, 0, stream>>>(user_emb, item_emb, x, acc, nu_elems, total);

    // CSR build (deterministic, no contended global atomics)
    hist_kernel<<<NBLK, 256, 0, stream>>>(h, ghist, E, EPB, NB);
    btot_kernel<<<NB, 256, 0, stream>>>(ghist, btot);
    bscan_kernel<<<1, 1024, 0, stream>>>(btot, bbase, NB, E);
    bofs_kernel<<<NB, 256, 0, stream>>>(ghist, bbase);
    scatter_kernel<<<NBLK, 256, 0, stream>>>(h, t, ghist, stg, E, EPB, NB);
    finalize_kernel<<<NB, 256, 0, stream>>>(stg, bbase, off, csr_t, N, E);

    init_A_kernel<<<gE, BLK, 0, stream>>>((float4*)Acsr, E);
    dcol0_kernel<<<gN, BLK, 0, stream>>>(off, dcolA, N);

    // ---- layer 0 ----
    prep_kernel<<<gTot, BLK, 0, stream>>>(x, xs, tailt, total);
    message_kernel<true, false, true, 0><<<gNodeWave, BLK, 0, stream>>>(
        off, csr_t, Acsr, prob, xs, tailt, dcolA, dcolB, out, acc, N);
    message_kernel<false, true, true, 1><<<gNodeWave, BLK, 0, stream>>>(
        off, csr_t, Acsr, prob, xs, tailt, dcolB, dcolA, out, acc, N);

    // ---- layer 1 ----
    prep_kernel<<<gTot, BLK, 0, stream>>>(out, xs, tailt, total);
    message_kernel<false, false, true, 0><<<gNodeWave, BLK, 0, stream>>>(
        off, csr_t, Acsr, prob, xs, tailt, dcolA, dcolB, x, acc, N);
    message_kernel<false, false, false, 2><<<gNodeWave, BLK, 0, stream>>>(
        off, csr_t, Acsr, prob, xs, tailt, dcolB, dcolA, x, acc, N);
}